// Round 2
// baseline (152.815 us; speedup 1.0000x reference)
//
#include <hip/hip_runtime.h>
#include <hip/hip_bf16.h>

#define BATCH 131072
#define PITCH 136   // bf16 elements per tile row (128 + 8 pad, keeps 16B alignment)

typedef __bf16 bf16x8 __attribute__((ext_vector_type(8)));
typedef float floatx4 __attribute__((ext_vector_type(4)));

__device__ __forceinline__ float fast_tanh(float x) {
    // tanh(x) = 1 - 2/(exp(2x)+1); exp overflow -> inf -> rcp -> 0 -> +1 (correct limit)
    float e = __expf(2.0f * x);
    return 1.0f - 2.0f * __builtin_amdgcn_rcpf(e + 1.0f);
}

__device__ __forceinline__ unsigned bpack(float a, float b) {
    unsigned short ua = __builtin_bit_cast(unsigned short, (__bf16)a);
    unsigned short ub = __builtin_bit_cast(unsigned short, (__bf16)b);
    return (unsigned)ua | ((unsigned)ub << 16);
}

// d_ws element layout (bf16):
// [0,16384)       W2s : B-frag swizzled W2              (GEMM1: h2pre = h1 @ W2)
// [16384,32768)   GTs : B-frag swizzled G^T, G=W2*C^T   (GEMM2: U = a2 @ G^T)
// [32768,36864)   W1s : B-frag swizzled W1, K pad to 32 (GEMM0: h1pre = [z|t] @ W1)
// [36864,38912)   W3s : B-frag swizzled W3, N pad to 16 (GEMM3: dz = h2 @ W3)
// swizzle: idx = ((kb*N + n)*4 + q)*8 + j  <->  B[k = kb*32 + q*8 + j][n]

__global__ void prep_kernel(const float* __restrict__ W1,
                            const float* __restrict__ W2,
                            const float* __restrict__ W3,
                            __bf16* __restrict__ ws) {
    int idx = blockIdx.x * 256 + threadIdx.x;
    if (idx < 16384) {
        int j = idx & 7, q = (idx >> 3) & 3, n = (idx >> 5) & 127, kb = idx >> 12;
        int k = kb * 32 + q * 8 + j;
        // W2s: B[k=h][n=g] = W2[h][g]
        ws[idx] = (__bf16)W2[k * 128 + n];
        // GTs: B[k=g][n=h] = G[h][g] = W2[h][g] * C[g][h], C[g][h] = sum_d W3[g][d]*W1[d][h]
        float c = 0.0f;
        #pragma unroll
        for (int d = 0; d < 8; ++d) c += W3[k * 8 + d] * W1[d * 128 + n];
        ws[16384 + idx] = (__bf16)(W2[n * 128 + k] * c);
    } else if (idx < 20480) {
        int t = idx - 16384;
        int j = t & 7, q = (t >> 3) & 3, n = t >> 5;   // kb==0 only
        int k = q * 8 + j;
        ws[32768 + t] = (k < 9) ? (__bf16)W1[k * 128 + n] : (__bf16)0.0f;
    } else if (idx < 22528) {
        int t = idx - 20480;
        int j = t & 7, q = (t >> 3) & 3, n = (t >> 5) & 15, kb = t >> 9;
        int k = kb * 32 + q * 8 + j;
        ws[36864 + t] = (n < 8) ? (__bf16)W3[k * 8 + n] : (__bf16)0.0f;
    }
}

// Occupancy pinned to EXACTLY 4 waves/EU (16 waves/CU, 4 blocks/CU):
//  - VGPR cap 128 (this kernel needs ~112; round-0 proved it fits at 128)
//  - amdgpu_waves_per_eu(4,4): a (4,_) open range made the backend chase
//    8 waves/EU by spilling to 64 VGPRs -> 200+ MB of HBM scratch traffic.
// LDS ~18.4 KB: only the per-wave transpose tile + biases; all weight
// B-frags (W1/W2/GT/W3) stream from L2-resident d_ws.
__global__ __launch_bounds__(256)
__attribute__((amdgpu_waves_per_eu(4, 4))) void cnf_main(
        const float* __restrict__ z, const float* __restrict__ t_ptr,
        const float* __restrict__ b1g, const float* __restrict__ b2g,
        const float* __restrict__ b3g, const __bf16* __restrict__ ws,
        float* __restrict__ out) {
    __shared__ float sb1[128];
    __shared__ float sb2[128];
    __shared__ __bf16 tile[4][16 * PITCH];  // per-wave private scratch, 4x4352 B

    const int tid = threadIdx.x;
    if (tid < 128) { sb1[tid] = b1g[tid]; sb2[tid] = b2g[tid]; }
    __syncthreads();

    const int lane = tid & 63;
    const int w = tid >> 6;
    const int p = lane & 15;       // C/D col, A row (sample), B col
    const int q = lane >> 4;       // quad
    __bf16* T = tile[w];
    const float tval = t_ptr[0];
    const float b3v = (p < 8) ? b3g[p] : 0.0f;
    const bf16x8* W2g = (const bf16x8*)ws;
    const bf16x8* GTv = (const bf16x8*)(ws + 16384);
    const bf16x8* W1g = (const bf16x8*)(ws + 32768);
    const bf16x8* W3v = (const bf16x8*)(ws + 36864);

    #pragma unroll
    for (int it = 0; it < 2; ++it) {
        const int s0 = blockIdx.x * 128 + it * 64 + w * 16;

        // ---- A-frag of X = [z | t | 0 pad to K=32]: A[m=p][k=q*8+j] ----
        bf16x8 ax;
        #pragma unroll
        for (int j = 0; j < 8; ++j) ax[j] = (__bf16)0.0f;
        if (q == 0) {
            const float4 z0 = ((const float4*)(z + (size_t)(s0 + p) * 8))[0];
            const float4 z1 = ((const float4*)(z + (size_t)(s0 + p) * 8))[1];
            ax[0] = (__bf16)z0.x; ax[1] = (__bf16)z0.y;
            ax[2] = (__bf16)z0.z; ax[3] = (__bf16)z0.w;
            ax[4] = (__bf16)z1.x; ax[5] = (__bf16)z1.y;
            ax[6] = (__bf16)z1.z; ax[7] = (__bf16)z1.w;
        } else if (q == 1) {
            ax[0] = (__bf16)tval;   // x[8] = t
        }

        // ---- GEMM0: h1pre = X @ W1 (single K-block), fused tanh/a1, tile h1 ----
        float a1c[32];
        #pragma unroll
        for (int nt = 0; nt < 8; ++nt) {
            const int n = nt * 16 + p;
            floatx4 acc = {0.f, 0.f, 0.f, 0.f};
            acc = __builtin_amdgcn_mfma_f32_16x16x32_bf16(ax, W1g[n * 4 + q], acc, 0, 0, 0);
            const float bn = sb1[n];
            #pragma unroll
            for (int r = 0; r < 4; ++r) {
                const float h1 = fast_tanh(acc[r] + bn);
                a1c[nt * 4 + r] = __builtin_fmaf(-h1, h1, 1.0f);
                T[(q * 4 + r) * PITCH + n] = (__bf16)h1;   // C/D layout -> tile
            }
        }
        // A-frags of h1 (wave-private LDS, in-order DS ops: no barrier needed)
        bf16x8 ah[4];
        #pragma unroll
        for (int kb = 0; kb < 4; ++kb)
            ah[kb] = *(const bf16x8*)&T[p * PITCH + kb * 32 + q * 8];

        // ---- GEMM1: h2pre = h1 @ W2, fused tanh, a2 -> tile, h2 packed bf16 regs ----
        unsigned h2p[16];
        #pragma unroll
        for (int nt = 0; nt < 8; ++nt) {
            const int n = nt * 16 + p;
            floatx4 acc = {0.f, 0.f, 0.f, 0.f};
            #pragma unroll
            for (int kb = 0; kb < 4; ++kb)
                acc = __builtin_amdgcn_mfma_f32_16x16x32_bf16(
                        ah[kb], W2g[(kb * 128 + n) * 4 + q], acc, 0, 0, 0);
            const float bn = sb2[n];
            float h2v[4];
            #pragma unroll
            for (int r = 0; r < 4; ++r) {
                const float h2 = fast_tanh(acc[r] + bn);
                h2v[r] = h2;
                const float a2 = __builtin_fmaf(-h2, h2, 1.0f);
                T[(q * 4 + r) * PITCH + n] = (__bf16)a2;
            }
            h2p[nt * 2 + 0] = bpack(h2v[0], h2v[1]);
            h2p[nt * 2 + 1] = bpack(h2v[2], h2v[3]);
        }
        bf16x8 aa[4];
        #pragma unroll
        for (int kb = 0; kb < 4; ++kb)
            aa[kb] = *(const bf16x8*)&T[p * PITCH + kb * 32 + q * 8];

        // ---- GEMM2: U = a2 @ G^T, fused dot with a1 (trace accumulation) ----
        float tr[4] = {0.f, 0.f, 0.f, 0.f};
        #pragma unroll
        for (int nt = 0; nt < 8; ++nt) {
            const int n = nt * 16 + p;
            floatx4 acc = {0.f, 0.f, 0.f, 0.f};
            #pragma unroll
            for (int kb = 0; kb < 4; ++kb)
                acc = __builtin_amdgcn_mfma_f32_16x16x32_bf16(
                        aa[kb], GTv[(kb * 128 + n) * 4 + q], acc, 0, 0, 0);
            #pragma unroll
            for (int r = 0; r < 4; ++r)
                tr[r] = __builtin_fmaf(a1c[nt * 4 + r], acc[r], tr[r]);
        }

        // ---- h2 packed regs -> tile -> A-frags ----
        #pragma unroll
        for (int i = 0; i < 16; ++i) {
            const int nt = i >> 1, rr = (i & 1) * 2;
            const int base = (q * 4 + rr) * PITCH + nt * 16 + p;
            T[base]         = __builtin_bit_cast(__bf16, (unsigned short)(h2p[i] & 0xffffu));
            T[base + PITCH] = __builtin_bit_cast(__bf16, (unsigned short)(h2p[i] >> 16));
        }
        bf16x8 ah2[4];
        #pragma unroll
        for (int kb = 0; kb < 4; ++kb)
            ah2[kb] = *(const bf16x8*)&T[p * PITCH + kb * 32 + q * 8];

        // ---- GEMM3: dz = h2 @ W3 (N padded to 16, only n=p<8 real) ----
        floatx4 acc3 = {0.f, 0.f, 0.f, 0.f};
        #pragma unroll
        for (int kb = 0; kb < 4; ++kb)
            acc3 = __builtin_amdgcn_mfma_f32_16x16x32_bf16(
                    ah2[kb], W3v[(kb * 16 + p) * 4 + q], acc3, 0, 0, 0);
        if (p < 8) {
            #pragma unroll
            for (int r = 0; r < 4; ++r)
                out[(size_t)(s0 + q * 4 + r) * 8 + p] = acc3[r] + b3v;
        }

        // ---- reduce trace over the 16 lanes of each quad; write -trace ----
        #pragma unroll
        for (int r = 0; r < 4; ++r) {
            float v = tr[r];
            v += __shfl_xor(v, 1, 64);
            v += __shfl_xor(v, 2, 64);
            v += __shfl_xor(v, 4, 64);
            v += __shfl_xor(v, 8, 64);
            tr[r] = v;
        }
        if (p == 0) {
            #pragma unroll
            for (int r = 0; r < 4; ++r)
                out[(size_t)BATCH * 8 + s0 + q * 4 + r] = -tr[r];
        }
    }
}

extern "C" void kernel_launch(void* const* d_in, const int* in_sizes, int n_in,
                              void* d_out, int out_size, void* d_ws, size_t ws_size,
                              hipStream_t stream) {
    const float* z  = (const float*)d_in[0];
    // d_in[1] = logp_z (unused by the reference math)
    const float* t  = (const float*)d_in[2];
    const float* W1 = (const float*)d_in[3];
    const float* b1 = (const float*)d_in[4];
    const float* W2 = (const float*)d_in[5];
    const float* b2 = (const float*)d_in[6];
    const float* W3 = (const float*)d_in[7];
    const float* b3 = (const float*)d_in[8];
    __bf16* ws = (__bf16*)d_ws;
    float* out = (float*)d_out;

    prep_kernel<<<88, 256, 0, stream>>>(W1, W2, W3, ws);
    cnf_main<<<1024, 256, 0, stream>>>(z, t, b1, b2, b3, ws, out);
}

// Round 3
// 110.771 us; speedup vs baseline: 1.3796x; 1.3796x over previous
//
#include <hip/hip_runtime.h>
#include <hip/hip_bf16.h>

#define BATCH 131072
#define PITCH 136   // bf16 elements per tile row (128 + 8 pad, keeps 16B alignment)

typedef __bf16 bf16x8 __attribute__((ext_vector_type(8)));
typedef float floatx4 __attribute__((ext_vector_type(4)));

__device__ __forceinline__ float fast_tanh(float x) {
    // tanh(x) = 1 - 2/(exp(2x)+1); exp overflow -> inf -> rcp -> 0 -> +1 (correct limit)
    float e = __expf(2.0f * x);
    return 1.0f - 2.0f * __builtin_amdgcn_rcpf(e + 1.0f);
}

__device__ __forceinline__ unsigned bpack(float a, float b) {
    unsigned short ua = __builtin_bit_cast(unsigned short, (__bf16)a);
    unsigned short ub = __builtin_bit_cast(unsigned short, (__bf16)b);
    return (unsigned)ua | ((unsigned)ub << 16);
}

// d_ws element layout (bf16):
// [0,16384)       W2s : B-frag swizzled W2              (GEMM1: h2pre = h1 @ W2)
// [16384,32768)   GTs : B-frag swizzled G^T, G=W2*C^T   (GEMM2: U = a2 @ G^T)
// [32768,36864)   W1s : B-frag swizzled W1, K pad to 32 (GEMM0: h1pre = [z|t] @ W1)
// [36864,38912)   W3s : B-frag swizzled W3, N pad to 16 (GEMM3: dz = h2 @ W3)
// swizzle: idx = ((kb*N + n)*4 + q)*8 + j  <->  B[k = kb*32 + q*8 + j][n]

__global__ void prep_kernel(const float* __restrict__ W1,
                            const float* __restrict__ W2,
                            const float* __restrict__ W3,
                            __bf16* __restrict__ ws) {
    int idx = blockIdx.x * 256 + threadIdx.x;
    if (idx < 16384) {
        int j = idx & 7, q = (idx >> 3) & 3, n = (idx >> 5) & 127, kb = idx >> 12;
        int k = kb * 32 + q * 8 + j;
        // W2s: B[k=h][n=g] = W2[h][g]
        ws[idx] = (__bf16)W2[k * 128 + n];
        // GTs: B[k=g][n=h] = G[h][g] = W2[h][g] * C[g][h], C[g][h] = sum_d W3[g][d]*W1[d][h]
        float c = 0.0f;
        #pragma unroll
        for (int d = 0; d < 8; ++d) c += W3[k * 8 + d] * W1[d * 128 + n];
        ws[16384 + idx] = (__bf16)(W2[n * 128 + k] * c);
    } else if (idx < 20480) {
        int t = idx - 16384;
        int j = t & 7, q = (t >> 3) & 3, n = t >> 5;   // kb==0 only
        int k = q * 8 + j;
        ws[32768 + t] = (k < 9) ? (__bf16)W1[k * 128 + n] : (__bf16)0.0f;
    } else if (idx < 22528) {
        int t = idx - 20480;
        int j = t & 7, q = (t >> 3) & 3, n = (t >> 5) & 15, kb = t >> 9;
        int k = kb * 32 + q * 8 + j;
        ws[36864 + t] = (n < 8) ? (__bf16)W3[k * 8 + n] : (__bf16)0.0f;
    }
}

// Occupancy strategy (evidence from rounds 0-2):
//  - __launch_bounds__(256, 2): VGPR budget 256 -> allocator lands at ~112-128
//    arch VGPRs with ZERO spill (round 0 proof: 128 VGPR, FETCH 8.8 MB).
//  - Any min-waves>=4 constraint (launch_bounds(,4) or waves_per_eu(4,4))
//    makes the backend split 64 arch + 64 acc and spill ~550 B/thread ->
//    ~200 MB HBM scratch traffic (rounds 1-2: FETCH 76 MB, WRITE 150 MB).
//  - Runtime occupancy follows ACTUAL VGPR count: <=128 VGPR + 18.4 KB LDS
//    -> 4 waves/EU, double round 0's LDS-limited 2 waves/EU.
// One 64-sample slab per block (no it-loop) keeps live state minimal.
__global__ __launch_bounds__(256, 2) void cnf_main(
        const float* __restrict__ z, const float* __restrict__ t_ptr,
        const float* __restrict__ b1g, const float* __restrict__ b2g,
        const float* __restrict__ b3g, const __bf16* __restrict__ ws,
        float* __restrict__ out) {
    __shared__ float sb1[128];
    __shared__ float sb2[128];
    __shared__ __bf16 tile[4][16 * PITCH];  // per-wave private scratch, 4x4352 B

    const int tid = threadIdx.x;
    if (tid < 128) { sb1[tid] = b1g[tid]; sb2[tid] = b2g[tid]; }
    __syncthreads();

    const int lane = tid & 63;
    const int w = tid >> 6;
    const int p = lane & 15;       // C/D col, A row (sample), B col
    const int q = lane >> 4;       // quad
    __bf16* T = tile[w];
    const float tval = t_ptr[0];
    const float b3v = (p < 8) ? b3g[p] : 0.0f;
    const bf16x8* W2g = (const bf16x8*)ws;
    const bf16x8* GTv = (const bf16x8*)(ws + 16384);
    const bf16x8* W1g = (const bf16x8*)(ws + 32768);
    const bf16x8* W3v = (const bf16x8*)(ws + 36864);

    const int s0 = blockIdx.x * 64 + w * 16;

    // ---- A-frag of X = [z | t | 0 pad to K=32]: A[m=p][k=q*8+j] ----
    bf16x8 ax;
    #pragma unroll
    for (int j = 0; j < 8; ++j) ax[j] = (__bf16)0.0f;
    if (q == 0) {
        const float4 z0 = ((const float4*)(z + (size_t)(s0 + p) * 8))[0];
        const float4 z1 = ((const float4*)(z + (size_t)(s0 + p) * 8))[1];
        ax[0] = (__bf16)z0.x; ax[1] = (__bf16)z0.y;
        ax[2] = (__bf16)z0.z; ax[3] = (__bf16)z0.w;
        ax[4] = (__bf16)z1.x; ax[5] = (__bf16)z1.y;
        ax[6] = (__bf16)z1.z; ax[7] = (__bf16)z1.w;
    } else if (q == 1) {
        ax[0] = (__bf16)tval;   // x[8] = t
    }

    // ---- GEMM0: h1pre = X @ W1 (single K-block), fused tanh/a1, tile h1 ----
    float a1c[32];
    #pragma unroll
    for (int nt = 0; nt < 8; ++nt) {
        const int n = nt * 16 + p;
        floatx4 acc = {0.f, 0.f, 0.f, 0.f};
        acc = __builtin_amdgcn_mfma_f32_16x16x32_bf16(ax, W1g[n * 4 + q], acc, 0, 0, 0);
        const float bn = sb1[n];
        #pragma unroll
        for (int r = 0; r < 4; ++r) {
            const float h1 = fast_tanh(acc[r] + bn);
            a1c[nt * 4 + r] = __builtin_fmaf(-h1, h1, 1.0f);
            T[(q * 4 + r) * PITCH + n] = (__bf16)h1;   // C/D layout -> tile
        }
    }
    // A-frags of h1 (wave-private LDS, in-order DS ops: no barrier needed)
    bf16x8 ah[4];
    #pragma unroll
    for (int kb = 0; kb < 4; ++kb)
        ah[kb] = *(const bf16x8*)&T[p * PITCH + kb * 32 + q * 8];

    // ---- GEMM1: h2pre = h1 @ W2, fused tanh, a2 -> tile, h2 packed bf16 regs ----
    unsigned h2p[16];
    #pragma unroll
    for (int nt = 0; nt < 8; ++nt) {
        const int n = nt * 16 + p;
        floatx4 acc = {0.f, 0.f, 0.f, 0.f};
        #pragma unroll
        for (int kb = 0; kb < 4; ++kb)
            acc = __builtin_amdgcn_mfma_f32_16x16x32_bf16(
                    ah[kb], W2g[(kb * 128 + n) * 4 + q], acc, 0, 0, 0);
        const float bn = sb2[n];
        float h2v[4];
        #pragma unroll
        for (int r = 0; r < 4; ++r) {
            const float h2 = fast_tanh(acc[r] + bn);
            h2v[r] = h2;
            const float a2 = __builtin_fmaf(-h2, h2, 1.0f);
            T[(q * 4 + r) * PITCH + n] = (__bf16)a2;
        }
        h2p[nt * 2 + 0] = bpack(h2v[0], h2v[1]);
        h2p[nt * 2 + 1] = bpack(h2v[2], h2v[3]);
    }
    bf16x8 aa[4];
    #pragma unroll
    for (int kb = 0; kb < 4; ++kb)
        aa[kb] = *(const bf16x8*)&T[p * PITCH + kb * 32 + q * 8];

    // ---- GEMM2: U = a2 @ G^T, fused dot with a1 (trace accumulation) ----
    float tr[4] = {0.f, 0.f, 0.f, 0.f};
    #pragma unroll
    for (int nt = 0; nt < 8; ++nt) {
        const int n = nt * 16 + p;
        floatx4 acc = {0.f, 0.f, 0.f, 0.f};
        #pragma unroll
        for (int kb = 0; kb < 4; ++kb)
            acc = __builtin_amdgcn_mfma_f32_16x16x32_bf16(
                    aa[kb], GTv[(kb * 128 + n) * 4 + q], acc, 0, 0, 0);
        #pragma unroll
        for (int r = 0; r < 4; ++r)
            tr[r] = __builtin_fmaf(a1c[nt * 4 + r], acc[r], tr[r]);
    }

    // ---- h2 packed regs -> tile -> A-frags ----
    #pragma unroll
    for (int i = 0; i < 16; ++i) {
        const int nt = i >> 1, rr = (i & 1) * 2;
        const int base = (q * 4 + rr) * PITCH + nt * 16 + p;
        T[base]         = __builtin_bit_cast(__bf16, (unsigned short)(h2p[i] & 0xffffu));
        T[base + PITCH] = __builtin_bit_cast(__bf16, (unsigned short)(h2p[i] >> 16));
    }
    bf16x8 ah2[4];
    #pragma unroll
    for (int kb = 0; kb < 4; ++kb)
        ah2[kb] = *(const bf16x8*)&T[p * PITCH + kb * 32 + q * 8];

    // ---- GEMM3: dz = h2 @ W3 (N padded to 16, only n=p<8 real) ----
    floatx4 acc3 = {0.f, 0.f, 0.f, 0.f};
    #pragma unroll
    for (int kb = 0; kb < 4; ++kb)
        acc3 = __builtin_amdgcn_mfma_f32_16x16x32_bf16(
                ah2[kb], W3v[(kb * 16 + p) * 4 + q], acc3, 0, 0, 0);
    if (p < 8) {
        #pragma unroll
        for (int r = 0; r < 4; ++r)
            out[(size_t)(s0 + q * 4 + r) * 8 + p] = acc3[r] + b3v;
    }

    // ---- reduce trace over the 16 lanes of each quad; write -trace ----
    #pragma unroll
    for (int r = 0; r < 4; ++r) {
        float v = tr[r];
        v += __shfl_xor(v, 1, 64);
        v += __shfl_xor(v, 2, 64);
        v += __shfl_xor(v, 4, 64);
        v += __shfl_xor(v, 8, 64);
        tr[r] = v;
    }
    if (p == 0) {
        #pragma unroll
        for (int r = 0; r < 4; ++r)
            out[(size_t)BATCH * 8 + s0 + q * 4 + r] = -tr[r];
    }
}

extern "C" void kernel_launch(void* const* d_in, const int* in_sizes, int n_in,
                              void* d_out, int out_size, void* d_ws, size_t ws_size,
                              hipStream_t stream) {
    const float* z  = (const float*)d_in[0];
    // d_in[1] = logp_z (unused by the reference math)
    const float* t  = (const float*)d_in[2];
    const float* W1 = (const float*)d_in[3];
    const float* b1 = (const float*)d_in[4];
    const float* W2 = (const float*)d_in[5];
    const float* b2 = (const float*)d_in[6];
    const float* W3 = (const float*)d_in[7];
    const float* b3 = (const float*)d_in[8];
    __bf16* ws = (__bf16*)d_ws;
    float* out = (float*)d_out;

    prep_kernel<<<88, 256, 0, stream>>>(W1, W2, W3, ws);
    cnf_main<<<2048, 256, 0, stream>>>(z, t, b1, b2, b3, ws, out);
}

// Round 5
// 102.995 us; speedup vs baseline: 1.4837x; 1.0755x over previous
//
#include <hip/hip_runtime.h>
#include <hip/hip_bf16.h>

#define BATCH 131072
#define PITCH 136   // bf16 elements per tile row (128 + 8 pad, keeps 16B alignment)

typedef __bf16 bf16x8 __attribute__((ext_vector_type(8)));
typedef float floatx4 __attribute__((ext_vector_type(4)));

__device__ __forceinline__ float fast_tanh(float x) {
    // tanh(x) = 1 - 2/(exp(2x)+1); exp overflow -> inf -> rcp -> 0 -> +1 (correct limit)
    float e = __expf(2.0f * x);
    return 1.0f - 2.0f * __builtin_amdgcn_rcpf(e + 1.0f);
}

__device__ __forceinline__ unsigned bpack(float a, float b) {
    unsigned short ua = __builtin_bit_cast(unsigned short, (__bf16)a);
    unsigned short ub = __builtin_bit_cast(unsigned short, (__bf16)b);
    return (unsigned)ua | ((unsigned)ub << 16);
}

// d_ws element layout (bf16):
// [0,16384)       W2s : B-frag swizzled W2              (GEMM1: h2pre = h1 @ W2)
// [16384,32768)   GTs : B-frag swizzled G^T, G=W2*C^T   (GEMM2: U = a2 @ G^T)
// [32768,36864)   W1s : B-frag swizzled W1, K pad to 32 (GEMM0: h1pre = [z|t] @ W1)
// [36864,38912)   W3s : B-frag swizzled W3, N pad to 16 (GEMM3: dz = h2 @ W3)
// swizzle: idx = ((kb*N + n)*4 + q)*8 + j  <->  B[k = kb*32 + q*8 + j][n]

__global__ void prep_kernel(const float* __restrict__ W1,
                            const float* __restrict__ W2,
                            const float* __restrict__ W3,
                            __bf16* __restrict__ ws) {
    int idx = blockIdx.x * 256 + threadIdx.x;
    if (idx < 16384) {
        int j = idx & 7, q = (idx >> 3) & 3, n = (idx >> 5) & 127, kb = idx >> 12;
        int k = kb * 32 + q * 8 + j;
        // W2s: B[k=h][n=g] = W2[h][g]
        ws[idx] = (__bf16)W2[k * 128 + n];
        // GTs: B[k=g][n=h] = G[h][g] = W2[h][g] * C[g][h], C[g][h] = sum_d W3[g][d]*W1[d][h]
        float c = 0.0f;
        #pragma unroll
        for (int d = 0; d < 8; ++d) c += W3[k * 8 + d] * W1[d * 128 + n];
        ws[16384 + idx] = (__bf16)(W2[n * 128 + k] * c);
    } else if (idx < 20480) {
        int t = idx - 16384;
        int j = t & 7, q = (t >> 3) & 3, n = t >> 5;   // kb==0 only
        int k = q * 8 + j;
        ws[32768 + t] = (k < 9) ? (__bf16)W1[k * 128 + n] : (__bf16)0.0f;
    } else if (idx < 22528) {
        int t = idx - 20480;
        int j = t & 7, q = (t >> 3) & 3, n = (t >> 5) & 15, kb = t >> 9;
        int k = kb * 32 + q * 8 + j;
        ws[36864 + t] = (n < 8) ? (__bf16)W3[k * 8 + n] : (__bf16)0.0f;
    }
}

// Structure rationale (rounds 0-3 evidence):
//  - W2/W1 staged in LDS beats streaming them from L2: round-3's L2-stream
//    version was 49.4 us steady vs <=41 us for the LDS-staged round-0 shape
//    (limited prefetch depth at ~72 VGPR -> serialized L2 round-trips).
//  - Occupancy lever: 512-thread blocks amortize ONE 40 KB W2s/W1s staging
//    across 8 waves. LDS = 32K(W2s)+8K(W1s)+1K(biases)+8x4.3K(tiles)=76.8 KB
//    -> 2 blocks/CU = 16 waves/CU = 4 waves/EU (2x round 0).
//  - launch_bounds(512,2) only: min-waves>=4 attrs made the backend spill to
//    64 VGPR (rounds 1-2, ~200 MB scratch HBM traffic). (256,2) landed at 72
//    VGPR spill-free; same per-wave code here.
__global__ __launch_bounds__(512, 2) void cnf_main(
        const float* __restrict__ z, const float* __restrict__ t_ptr,
        const float* __restrict__ b1g, const float* __restrict__ b2g,
        const float* __restrict__ b3g, const __bf16* __restrict__ ws,
        float* __restrict__ out) {
    __shared__ __bf16 sW2s[16384];          // 32 KB
    __shared__ __bf16 sW1s[4096];           // 8 KB
    __shared__ float sb1[128];
    __shared__ float sb2[128];
    __shared__ __bf16 tile[8][16 * PITCH];  // per-wave private scratch, 8x4352 B

    const int tid = threadIdx.x;
    {
        uint4* dst = (uint4*)sW2s;
        const uint4* src = (const uint4*)ws;
        #pragma unroll
        for (int i = 0; i < 4; ++i) dst[tid + i * 512] = src[tid + i * 512];
        uint4* dst1 = (uint4*)sW1s;
        const uint4* src1 = (const uint4*)(ws + 32768);
        dst1[tid] = src1[tid & 511];
        if (tid < 128) { sb1[tid] = b1g[tid]; sb2[tid] = b2g[tid]; }
    }
    __syncthreads();

    const int lane = tid & 63;
    const int w = tid >> 6;
    const int p = lane & 15;       // C/D col, A row (sample), B col
    const int q = lane >> 4;       // quad
    __bf16* T = tile[w];
    const float tval = t_ptr[0];
    const float b3v = (p < 8) ? b3g[p] : 0.0f;
    const bf16x8* W2sv = (const bf16x8*)sW2s;
    const bf16x8* W1sv = (const bf16x8*)sW1s;
    const bf16x8* GTv  = (const bf16x8*)(ws + 16384);
    const bf16x8* W3v  = (const bf16x8*)(ws + 36864);

    #pragma unroll
    for (int it = 0; it < 2; ++it) {
        const int s0 = blockIdx.x * 256 + it * 128 + w * 16;

        // ---- A-frag of X = [z | t | 0 pad to K=32]: A[m=p][k=q*8+j] ----
        bf16x8 ax;
        #pragma unroll
        for (int j = 0; j < 8; ++j) ax[j] = (__bf16)0.0f;
        if (q == 0) {
            const float4 z0 = ((const float4*)(z + (size_t)(s0 + p) * 8))[0];
            const float4 z1 = ((const float4*)(z + (size_t)(s0 + p) * 8))[1];
            ax[0] = (__bf16)z0.x; ax[1] = (__bf16)z0.y;
            ax[2] = (__bf16)z0.z; ax[3] = (__bf16)z0.w;
            ax[4] = (__bf16)z1.x; ax[5] = (__bf16)z1.y;
            ax[6] = (__bf16)z1.z; ax[7] = (__bf16)z1.w;
        } else if (q == 1) {
            ax[0] = (__bf16)tval;   // x[8] = t
        }

        // ---- GEMM0: h1pre = X @ W1 (single K-block), fused tanh/a1, tile h1 ----
        float a1c[32];
        #pragma unroll
        for (int nt = 0; nt < 8; ++nt) {
            const int n = nt * 16 + p;
            floatx4 acc = {0.f, 0.f, 0.f, 0.f};
            acc = __builtin_amdgcn_mfma_f32_16x16x32_bf16(ax, W1sv[n * 4 + q], acc, 0, 0, 0);
            const float bn = sb1[n];
            #pragma unroll
            for (int r = 0; r < 4; ++r) {
                const float h1 = fast_tanh(acc[r] + bn);
                a1c[nt * 4 + r] = __builtin_fmaf(-h1, h1, 1.0f);
                T[(q * 4 + r) * PITCH + n] = (__bf16)h1;   // C/D layout -> tile
            }
        }
        // A-frags of h1 (wave-private LDS, in-order DS ops: no barrier needed)
        bf16x8 ah[4];
        #pragma unroll
        for (int kb = 0; kb < 4; ++kb)
            ah[kb] = *(const bf16x8*)&T[p * PITCH + kb * 32 + q * 8];

        // ---- GEMM1: h2pre = h1 @ W2, fused tanh, a2 -> tile, h2 packed bf16 regs ----
        unsigned h2p[16];
        #pragma unroll
        for (int nt = 0; nt < 8; ++nt) {
            const int n = nt * 16 + p;
            floatx4 acc = {0.f, 0.f, 0.f, 0.f};
            #pragma unroll
            for (int kb = 0; kb < 4; ++kb)
                acc = __builtin_amdgcn_mfma_f32_16x16x32_bf16(
                        ah[kb], W2sv[(kb * 128 + n) * 4 + q], acc, 0, 0, 0);
            const float bn = sb2[n];
            float h2v[4];
            #pragma unroll
            for (int r = 0; r < 4; ++r) {
                const float h2 = fast_tanh(acc[r] + bn);
                h2v[r] = h2;
                const float a2 = __builtin_fmaf(-h2, h2, 1.0f);
                T[(q * 4 + r) * PITCH + n] = (__bf16)a2;
            }
            h2p[nt * 2 + 0] = bpack(h2v[0], h2v[1]);
            h2p[nt * 2 + 1] = bpack(h2v[2], h2v[3]);
        }
        bf16x8 aa[4];
        #pragma unroll
        for (int kb = 0; kb < 4; ++kb)
            aa[kb] = *(const bf16x8*)&T[p * PITCH + kb * 32 + q * 8];

        // ---- GEMM2: U = a2 @ G^T, fused dot with a1 (trace accumulation) ----
        float tr[4] = {0.f, 0.f, 0.f, 0.f};
        #pragma unroll
        for (int nt = 0; nt < 8; ++nt) {
            const int n = nt * 16 + p;
            floatx4 acc = {0.f, 0.f, 0.f, 0.f};
            #pragma unroll
            for (int kb = 0; kb < 4; ++kb)
                acc = __builtin_amdgcn_mfma_f32_16x16x32_bf16(
                        aa[kb], GTv[(kb * 128 + n) * 4 + q], acc, 0, 0, 0);
            #pragma unroll
            for (int r = 0; r < 4; ++r)
                tr[r] = __builtin_fmaf(a1c[nt * 4 + r], acc[r], tr[r]);
        }

        // ---- h2 packed regs -> tile -> A-frags ----
        #pragma unroll
        for (int i = 0; i < 16; ++i) {
            const int nt = i >> 1, rr = (i & 1) * 2;
            const int base = (q * 4 + rr) * PITCH + nt * 16 + p;
            T[base]         = __builtin_bit_cast(__bf16, (unsigned short)(h2p[i] & 0xffffu));
            T[base + PITCH] = __builtin_bit_cast(__bf16, (unsigned short)(h2p[i] >> 16));
        }
        bf16x8 ah2[4];
        #pragma unroll
        for (int kb = 0; kb < 4; ++kb)
            ah2[kb] = *(const bf16x8*)&T[p * PITCH + kb * 32 + q * 8];

        // ---- GEMM3: dz = h2 @ W3 (N padded to 16, only n=p<8 real) ----
        floatx4 acc3 = {0.f, 0.f, 0.f, 0.f};
        #pragma unroll
        for (int kb = 0; kb < 4; ++kb)
            acc3 = __builtin_amdgcn_mfma_f32_16x16x32_bf16(
                    ah2[kb], W3v[(kb * 16 + p) * 4 + q], acc3, 0, 0, 0);
        if (p < 8) {
            #pragma unroll
            for (int r = 0; r < 4; ++r)
                out[(size_t)(s0 + q * 4 + r) * 8 + p] = acc3[r] + b3v;
        }

        // ---- reduce trace over the 16 lanes of each quad; write -trace ----
        #pragma unroll
        for (int r = 0; r < 4; ++r) {
            float v = tr[r];
            v += __shfl_xor(v, 1, 64);
            v += __shfl_xor(v, 2, 64);
            v += __shfl_xor(v, 4, 64);
            v += __shfl_xor(v, 8, 64);
            tr[r] = v;
        }
        if (p == 0) {
            #pragma unroll
            for (int r = 0; r < 4; ++r)
                out[(size_t)BATCH * 8 + s0 + q * 4 + r] = -tr[r];
        }
    }
}

extern "C" void kernel_launch(void* const* d_in, const int* in_sizes, int n_in,
                              void* d_out, int out_size, void* d_ws, size_t ws_size,
                              hipStream_t stream) {
    const float* z  = (const float*)d_in[0];
    // d_in[1] = logp_z (unused by the reference math)
    const float* t  = (const float*)d_in[2];
    const float* W1 = (const float*)d_in[3];
    const float* b1 = (const float*)d_in[4];
    const float* W2 = (const float*)d_in[5];
    const float* b2 = (const float*)d_in[6];
    const float* W3 = (const float*)d_in[7];
    const float* b3 = (const float*)d_in[8];
    __bf16* ws = (__bf16*)d_ws;
    float* out = (float*)d_out;

    prep_kernel<<<88, 256, 0, stream>>>(W1, W2, W3, ws);
    cnf_main<<<512, 512, 0, stream>>>(z, t, b1, b2, b3, ws, out);
}